// Round 10
// baseline (69.262 us; speedup 1.0000x reference)
//
#include <hip/hip_runtime.h>

// PIT loss: x,y [B=8, C=4, CH=2, T=262144] f32. D = CH*T = 524288.
// dists[b,i,j] = (sum(y[b,i]^2) + sum(x[b,j]^2) - 2*sum(x[b,j]*y[b,i])) / D
// total = sum_b min_p sum_i dists[b,i,perm[p][i]]; assignments[b] = argmin perm.
//
// R10: stream-locality curve, next point. TPB 512->1024, BPB 32->16
// (128 blocks): 1024 machine-wide read streams (was 2048), 128 KiB
// contiguous ownership each. Half the CUs idle — acceptable iff HBM-bound.
// nt loads, transposed ws, coalesced finalize kept.

#define BATCH   8
#define CDIM    4
#define DLEN    (2 * 262144)        // 524288 scalars per (b, c)
#define F4_PER_C (DLEN / 4)         // 131072 float4 per channel
#define BPB     16                  // blocks per batch
#define TPB     1024
#define NVAL    24                  // 4 sx + 4 sy + 16 cross
#define NBLOCKS (BATCH * BPB)       // 128
#define NWAVES  (TPB / 64)          // 16

typedef float f4 __attribute__((ext_vector_type(4)));

// itertools.permutations(range(4)) lexicographic order
__device__ __constant__ int PERMS[24][4] = {
    {0,1,2,3},{0,1,3,2},{0,2,1,3},{0,2,3,1},{0,3,1,2},{0,3,2,1},
    {1,0,2,3},{1,0,3,2},{1,2,0,3},{1,2,3,0},{1,3,0,2},{1,3,2,0},
    {2,0,1,3},{2,0,3,1},{2,1,0,3},{2,1,3,0},{2,3,0,1},{2,3,1,0},
    {3,0,1,2},{3,0,2,1},{3,1,0,2},{3,1,2,0},{3,2,0,1},{3,2,1,0}
};

__global__ __launch_bounds__(TPB) void pit_reduce(const float* __restrict__ x,
                                                  const float* __restrict__ y,
                                                  float* __restrict__ ws) {
    const int b   = blockIdx.x / BPB;
    const int blk = blockIdx.x % BPB;
    const int tid = threadIdx.x;

    const int f4_per_block = F4_PER_C / BPB;     // 8192
    const int iters        = f4_per_block / TPB; // 8
    const int base_f4      = blk * f4_per_block;

    const f4* __restrict__ xb = (const f4*)(x + (size_t)b * CDIM * DLEN);
    const f4* __restrict__ yb = (const f4*)(y + (size_t)b * CDIM * DLEN);

    float sx[4] = {0.f, 0.f, 0.f, 0.f};
    float sy[4] = {0.f, 0.f, 0.f, 0.f};
    float cr[4][4] = {};

    for (int it = 0; it < iters; ++it) {
        const int p = base_f4 + it * TPB + tid;
        f4 xv[4], yv[4];
#pragma unroll
        for (int c = 0; c < 4; ++c)
            xv[c] = __builtin_nontemporal_load(&xb[(size_t)c * F4_PER_C + p]);
#pragma unroll
        for (int c = 0; c < 4; ++c)
            yv[c] = __builtin_nontemporal_load(&yb[(size_t)c * F4_PER_C + p]);
#pragma unroll
        for (int c = 0; c < 4; ++c) {
            sx[c] += xv[c].x * xv[c].x + xv[c].y * xv[c].y +
                     xv[c].z * xv[c].z + xv[c].w * xv[c].w;
            sy[c] += yv[c].x * yv[c].x + yv[c].y * yv[c].y +
                     yv[c].z * yv[c].z + yv[c].w * yv[c].w;
        }
#pragma unroll
        for (int i = 0; i < 4; ++i)
#pragma unroll
            for (int j = 0; j < 4; ++j)
                cr[i][j] += yv[i].x * xv[j].x + yv[i].y * xv[j].y +
                            yv[i].z * xv[j].z + yv[i].w * xv[j].w;
    }

    // pack 24 accumulators: [0..3]=sx, [4..7]=sy, [8..23]=cr[i][j]
    float v[NVAL];
#pragma unroll
    for (int c = 0; c < 4; ++c) { v[c] = sx[c]; v[4 + c] = sy[c]; }
#pragma unroll
    for (int i = 0; i < 4; ++i)
#pragma unroll
        for (int j = 0; j < 4; ++j) v[8 + i * 4 + j] = cr[i][j];

    // wave64 tree reduce (deterministic)
#pragma unroll
    for (int k = 0; k < NVAL; ++k) {
#pragma unroll
        for (int off = 32; off > 0; off >>= 1)
            v[k] += __shfl_down(v[k], off);
    }

    __shared__ float red[NWAVES][NVAL];
    const int wave = tid >> 6, lane = tid & 63;
    if (lane == 0) {
#pragma unroll
        for (int k = 0; k < NVAL; ++k) red[wave][k] = v[k];
    }
    __syncthreads();
    if (tid < NVAL) {
        float s = 0.f;
#pragma unroll
        for (int w = 0; w < NWAVES; ++w) s += red[w][tid];
        // transposed: ws[k][global_block] -> contiguous per-k rows of 128 floats
        ws[(size_t)tid * NBLOCKS + (b * BPB + blk)] = s;
    }
}

__global__ __launch_bounds__(256) void pit_finalize(const float* __restrict__ ws,
                                                    float* __restrict__ out) {
    __shared__ double stage[BATCH][NVAL];   // summed partials
    __shared__ double dists[BATCH][4][4];
    __shared__ double mins[BATCH];
    const int tid = threadIdx.x;

    // 192 active threads, (k major, b minor): the whole block reads the
    // 12 KiB ws span fully coalesced as float4.
    if (tid < BATCH * NVAL) {
        const int k = tid / BATCH, bb = tid % BATCH;
        const f4* p = (const f4*)(ws + (size_t)k * NBLOCKS + bb * BPB);
        double s0 = 0.0, s1 = 0.0, s2 = 0.0, s3 = 0.0;
        {                                        // 4 f4 = 16 partials
            f4 a = p[0], c = p[1], d = p[2], e = p[3];
            s0 = (double)a.x + (double)a.y + (double)a.z + (double)a.w;
            s1 = (double)c.x + (double)c.y + (double)c.z + (double)c.w;
            s2 = (double)d.x + (double)d.y + (double)d.z + (double)d.w;
            s3 = (double)e.x + (double)e.y + (double)e.z + (double)e.w;
        }
        stage[bb][k] = (s0 + s1) + (s2 + s3);
    }
    __syncthreads();

    if (tid < BATCH * 16) {                 // 128 threads
        const int bb = tid / 16, ij = tid % 16, i = ij / 4, j = ij % 4;
        dists[bb][i][j] = (stage[bb][4 + i] + stage[bb][j]
                           - 2.0 * stage[bb][8 + i * 4 + j]) / (double)DLEN;
    }
    __syncthreads();

    if (tid < BATCH) {
        const int bb = tid;
        double best = 1e300;
        int bestp = 0;
        for (int p = 0; p < 24; ++p) {
            double c = 0.0;
#pragma unroll
            for (int i = 0; i < 4; ++i) c += dists[bb][i][PERMS[p][i]];
            if (c < best) { best = c; bestp = p; }   // strict < => first min (jnp.argmin)
        }
        mins[bb] = best;
#pragma unroll
        for (int i = 0; i < 4; ++i)
            out[1 + bb * 4 + i] = (float)PERMS[bestp][i];
    }
    __syncthreads();

    if (tid == 0) {
        double tot = 0.0;
        for (int bb = 0; bb < BATCH; ++bb) tot += mins[bb];
        out[0] = (float)tot;
    }
}

extern "C" void kernel_launch(void* const* d_in, const int* in_sizes, int n_in,
                              void* d_out, int out_size, void* d_ws, size_t ws_size,
                              hipStream_t stream) {
    const float* x = (const float*)d_in[0];
    const float* y = (const float*)d_in[1];
    float* out = (float*)d_out;
    float* ws  = (float*)d_ws;     // needs NVAL*NBLOCKS*4 = 12288 bytes

    pit_reduce<<<NBLOCKS, TPB, 0, stream>>>(x, y, ws);
    pit_finalize<<<1, 256, 0, stream>>>(ws, out);
}

// Round 11
// 62.940 us; speedup vs baseline: 1.1004x; 1.1004x over previous
//
#include <hip/hip_runtime.h>

// PIT loss: x,y [B=8, C=4, CH=2, T=262144] f32. D = CH*T = 524288.
// dists[b,i,j] = (sum(y[b,i]^2) + sum(x[b,j]^2) - 2*sum(x[b,j]*y[b,i])) / D
// total = sum_b min_p sum_i dists[b,i,perm[p][i]]; assignments[b] = argmin perm.
//
// R11: clean re-probe of the 1024-stream point. R10's TPB=1024 capped VGPR
// at 64 -> 54 MB scratch spill (confound). Keep TPB=512 (VGPR budget 128,
// kernel needs ~108), BPB 32->16: 128 blocks, 16 iters/thread, 128 KiB
// contiguous ownership per stream. Only stream count changes vs R9.

#define BATCH   8
#define CDIM    4
#define DLEN    (2 * 262144)        // 524288 scalars per (b, c)
#define F4_PER_C (DLEN / 4)         // 131072 float4 per channel
#define BPB     16                  // blocks per batch
#define TPB     512
#define NVAL    24                  // 4 sx + 4 sy + 16 cross
#define NBLOCKS (BATCH * BPB)       // 128
#define NWAVES  (TPB / 64)          // 8

typedef float f4 __attribute__((ext_vector_type(4)));

// itertools.permutations(range(4)) lexicographic order
__device__ __constant__ int PERMS[24][4] = {
    {0,1,2,3},{0,1,3,2},{0,2,1,3},{0,2,3,1},{0,3,1,2},{0,3,2,1},
    {1,0,2,3},{1,0,3,2},{1,2,0,3},{1,2,3,0},{1,3,0,2},{1,3,2,0},
    {2,0,1,3},{2,0,3,1},{2,1,0,3},{2,1,3,0},{2,3,0,1},{2,3,1,0},
    {3,0,1,2},{3,0,2,1},{3,1,0,2},{3,1,2,0},{3,2,0,1},{3,2,1,0}
};

__global__ __launch_bounds__(TPB) void pit_reduce(const float* __restrict__ x,
                                                  const float* __restrict__ y,
                                                  float* __restrict__ ws) {
    const int b   = blockIdx.x / BPB;
    const int blk = blockIdx.x % BPB;
    const int tid = threadIdx.x;

    const int f4_per_block = F4_PER_C / BPB;     // 8192
    const int iters        = f4_per_block / TPB; // 16
    const int base_f4      = blk * f4_per_block;

    const f4* __restrict__ xb = (const f4*)(x + (size_t)b * CDIM * DLEN);
    const f4* __restrict__ yb = (const f4*)(y + (size_t)b * CDIM * DLEN);

    float sx[4] = {0.f, 0.f, 0.f, 0.f};
    float sy[4] = {0.f, 0.f, 0.f, 0.f};
    float cr[4][4] = {};

    for (int it = 0; it < iters; ++it) {
        const int p = base_f4 + it * TPB + tid;
        f4 xv[4], yv[4];
#pragma unroll
        for (int c = 0; c < 4; ++c)
            xv[c] = __builtin_nontemporal_load(&xb[(size_t)c * F4_PER_C + p]);
#pragma unroll
        for (int c = 0; c < 4; ++c)
            yv[c] = __builtin_nontemporal_load(&yb[(size_t)c * F4_PER_C + p]);
#pragma unroll
        for (int c = 0; c < 4; ++c) {
            sx[c] += xv[c].x * xv[c].x + xv[c].y * xv[c].y +
                     xv[c].z * xv[c].z + xv[c].w * xv[c].w;
            sy[c] += yv[c].x * yv[c].x + yv[c].y * yv[c].y +
                     yv[c].z * yv[c].z + yv[c].w * yv[c].w;
        }
#pragma unroll
        for (int i = 0; i < 4; ++i)
#pragma unroll
            for (int j = 0; j < 4; ++j)
                cr[i][j] += yv[i].x * xv[j].x + yv[i].y * xv[j].y +
                            yv[i].z * xv[j].z + yv[i].w * xv[j].w;
    }

    // pack 24 accumulators: [0..3]=sx, [4..7]=sy, [8..23]=cr[i][j]
    float v[NVAL];
#pragma unroll
    for (int c = 0; c < 4; ++c) { v[c] = sx[c]; v[4 + c] = sy[c]; }
#pragma unroll
    for (int i = 0; i < 4; ++i)
#pragma unroll
        for (int j = 0; j < 4; ++j) v[8 + i * 4 + j] = cr[i][j];

    // wave64 tree reduce (deterministic)
#pragma unroll
    for (int k = 0; k < NVAL; ++k) {
#pragma unroll
        for (int off = 32; off > 0; off >>= 1)
            v[k] += __shfl_down(v[k], off);
    }

    __shared__ float red[NWAVES][NVAL];
    const int wave = tid >> 6, lane = tid & 63;
    if (lane == 0) {
#pragma unroll
        for (int k = 0; k < NVAL; ++k) red[wave][k] = v[k];
    }
    __syncthreads();
    if (tid < NVAL) {
        float s = 0.f;
#pragma unroll
        for (int w = 0; w < NWAVES; ++w) s += red[w][tid];
        // transposed: ws[k][global_block] -> contiguous per-k rows of 128 floats
        ws[(size_t)tid * NBLOCKS + (b * BPB + blk)] = s;
    }
}

__global__ __launch_bounds__(256) void pit_finalize(const float* __restrict__ ws,
                                                    float* __restrict__ out) {
    __shared__ double stage[BATCH][NVAL];   // summed partials
    __shared__ double dists[BATCH][4][4];
    __shared__ double mins[BATCH];
    const int tid = threadIdx.x;

    // 192 active threads, (k major, b minor): the whole block reads the
    // 12 KiB ws span fully coalesced as float4.
    if (tid < BATCH * NVAL) {
        const int k = tid / BATCH, bb = tid % BATCH;
        const f4* p = (const f4*)(ws + (size_t)k * NBLOCKS + bb * BPB);
        double s0, s1, s2, s3;
        {                                        // 4 f4 = 16 partials
            f4 a = p[0], c = p[1], d = p[2], e = p[3];
            s0 = (double)a.x + (double)a.y + (double)a.z + (double)a.w;
            s1 = (double)c.x + (double)c.y + (double)c.z + (double)c.w;
            s2 = (double)d.x + (double)d.y + (double)d.z + (double)d.w;
            s3 = (double)e.x + (double)e.y + (double)e.z + (double)e.w;
        }
        stage[bb][k] = (s0 + s1) + (s2 + s3);
    }
    __syncthreads();

    if (tid < BATCH * 16) {                 // 128 threads
        const int bb = tid / 16, ij = tid % 16, i = ij / 4, j = ij % 4;
        dists[bb][i][j] = (stage[bb][4 + i] + stage[bb][j]
                           - 2.0 * stage[bb][8 + i * 4 + j]) / (double)DLEN;
    }
    __syncthreads();

    if (tid < BATCH) {
        const int bb = tid;
        double best = 1e300;
        int bestp = 0;
        for (int p = 0; p < 24; ++p) {
            double c = 0.0;
#pragma unroll
            for (int i = 0; i < 4; ++i) c += dists[bb][i][PERMS[p][i]];
            if (c < best) { best = c; bestp = p; }   // strict < => first min (jnp.argmin)
        }
        mins[bb] = best;
#pragma unroll
        for (int i = 0; i < 4; ++i)
            out[1 + bb * 4 + i] = (float)PERMS[bestp][i];
    }
    __syncthreads();

    if (tid == 0) {
        double tot = 0.0;
        for (int bb = 0; bb < BATCH; ++bb) tot += mins[bb];
        out[0] = (float)tot;
    }
}

extern "C" void kernel_launch(void* const* d_in, const int* in_sizes, int n_in,
                              void* d_out, int out_size, void* d_ws, size_t ws_size,
                              hipStream_t stream) {
    const float* x = (const float*)d_in[0];
    const float* y = (const float*)d_in[1];
    float* out = (float*)d_out;
    float* ws  = (float*)d_ws;     // needs NVAL*NBLOCKS*4 = 12288 bytes

    pit_reduce<<<NBLOCKS, TPB, 0, stream>>>(x, y, ws);
    pit_finalize<<<1, 256, 0, stream>>>(ws, out);
}

// Round 12
// 35.853 us; speedup vs baseline: 1.9318x; 1.7555x over previous
//
#include <hip/hip_runtime.h>

// PIT loss: x,y [B=8, C=4, CH=2, T=262144] f32. D = CH*T = 524288.
// dists[b,i,j] = (sum(y[b,i]^2) + sum(x[b,j]^2) - 2*sum(x[b,j]*y[b,i])) / D
// total = sum_b min_p sum_i dists[b,i,perm[p][i]]; assignments[b] = argmin perm.
//
// R12: third attempt at the 1024-stream point, register pressure pinned.
// R10 spilled via the TPB=1024 VGPR cap; R11 spilled via full unroll of the
// 16-iteration loop. Here: TPB=512, BPB=16, #pragma unroll 8 -> identical
// codegen shape to the no-spill R9 (8 load/compute groups per unrolled
// body), executed twice. Only machine-wide stream count changes vs R9
// (2048 -> 1024, 128 KiB contiguous ownership per stream).

#define BATCH   8
#define CDIM    4
#define DLEN    (2 * 262144)        // 524288 scalars per (b, c)
#define F4_PER_C (DLEN / 4)         // 131072 float4 per channel
#define BPB     16                  // blocks per batch
#define TPB     512
#define NVAL    24                  // 4 sx + 4 sy + 16 cross
#define NBLOCKS (BATCH * BPB)       // 128
#define NWAVES  (TPB / 64)          // 8

typedef float f4 __attribute__((ext_vector_type(4)));

// itertools.permutations(range(4)) lexicographic order
__device__ __constant__ int PERMS[24][4] = {
    {0,1,2,3},{0,1,3,2},{0,2,1,3},{0,2,3,1},{0,3,1,2},{0,3,2,1},
    {1,0,2,3},{1,0,3,2},{1,2,0,3},{1,2,3,0},{1,3,0,2},{1,3,2,0},
    {2,0,1,3},{2,0,3,1},{2,1,0,3},{2,1,3,0},{2,3,0,1},{2,3,1,0},
    {3,0,1,2},{3,0,2,1},{3,1,0,2},{3,1,2,0},{3,2,0,1},{3,2,1,0}
};

__global__ __launch_bounds__(TPB) void pit_reduce(const float* __restrict__ x,
                                                  const float* __restrict__ y,
                                                  float* __restrict__ ws) {
    const int b   = blockIdx.x / BPB;
    const int blk = blockIdx.x % BPB;
    const int tid = threadIdx.x;

    const int f4_per_block = F4_PER_C / BPB;     // 8192
    const int iters        = f4_per_block / TPB; // 16
    const int base_f4      = blk * f4_per_block;

    const f4* __restrict__ xb = (const f4*)(x + (size_t)b * CDIM * DLEN);
    const f4* __restrict__ yb = (const f4*)(y + (size_t)b * CDIM * DLEN);

    float sx[4] = {0.f, 0.f, 0.f, 0.f};
    float sy[4] = {0.f, 0.f, 0.f, 0.f};
    float cr[4][4] = {};

#pragma unroll 8
    for (int it = 0; it < iters; ++it) {
        const int p = base_f4 + it * TPB + tid;
        f4 xv[4], yv[4];
#pragma unroll
        for (int c = 0; c < 4; ++c)
            xv[c] = __builtin_nontemporal_load(&xb[(size_t)c * F4_PER_C + p]);
#pragma unroll
        for (int c = 0; c < 4; ++c)
            yv[c] = __builtin_nontemporal_load(&yb[(size_t)c * F4_PER_C + p]);
#pragma unroll
        for (int c = 0; c < 4; ++c) {
            sx[c] += xv[c].x * xv[c].x + xv[c].y * xv[c].y +
                     xv[c].z * xv[c].z + xv[c].w * xv[c].w;
            sy[c] += yv[c].x * yv[c].x + yv[c].y * yv[c].y +
                     yv[c].z * yv[c].z + yv[c].w * yv[c].w;
        }
#pragma unroll
        for (int i = 0; i < 4; ++i)
#pragma unroll
            for (int j = 0; j < 4; ++j)
                cr[i][j] += yv[i].x * xv[j].x + yv[i].y * xv[j].y +
                            yv[i].z * xv[j].z + yv[i].w * xv[j].w;
    }

    // pack 24 accumulators: [0..3]=sx, [4..7]=sy, [8..23]=cr[i][j]
    float v[NVAL];
#pragma unroll
    for (int c = 0; c < 4; ++c) { v[c] = sx[c]; v[4 + c] = sy[c]; }
#pragma unroll
    for (int i = 0; i < 4; ++i)
#pragma unroll
        for (int j = 0; j < 4; ++j) v[8 + i * 4 + j] = cr[i][j];

    // wave64 tree reduce (deterministic)
#pragma unroll
    for (int k = 0; k < NVAL; ++k) {
#pragma unroll
        for (int off = 32; off > 0; off >>= 1)
            v[k] += __shfl_down(v[k], off);
    }

    __shared__ float red[NWAVES][NVAL];
    const int wave = tid >> 6, lane = tid & 63;
    if (lane == 0) {
#pragma unroll
        for (int k = 0; k < NVAL; ++k) red[wave][k] = v[k];
    }
    __syncthreads();
    if (tid < NVAL) {
        float s = 0.f;
#pragma unroll
        for (int w = 0; w < NWAVES; ++w) s += red[w][tid];
        // transposed: ws[k][global_block] -> contiguous per-k rows of 128 floats
        ws[(size_t)tid * NBLOCKS + (b * BPB + blk)] = s;
    }
}

__global__ __launch_bounds__(256) void pit_finalize(const float* __restrict__ ws,
                                                    float* __restrict__ out) {
    __shared__ double stage[BATCH][NVAL];   // summed partials
    __shared__ double dists[BATCH][4][4];
    __shared__ double mins[BATCH];
    const int tid = threadIdx.x;

    // 192 active threads, (k major, b minor): the whole block reads the
    // 12 KiB ws span fully coalesced as float4.
    if (tid < BATCH * NVAL) {
        const int k = tid / BATCH, bb = tid % BATCH;
        const f4* p = (const f4*)(ws + (size_t)k * NBLOCKS + bb * BPB);
        double s0, s1, s2, s3;
        {                                        // 4 f4 = 16 partials
            f4 a = p[0], c = p[1], d = p[2], e = p[3];
            s0 = (double)a.x + (double)a.y + (double)a.z + (double)a.w;
            s1 = (double)c.x + (double)c.y + (double)c.z + (double)c.w;
            s2 = (double)d.x + (double)d.y + (double)d.z + (double)d.w;
            s3 = (double)e.x + (double)e.y + (double)e.z + (double)e.w;
        }
        stage[bb][k] = (s0 + s1) + (s2 + s3);
    }
    __syncthreads();

    if (tid < BATCH * 16) {                 // 128 threads
        const int bb = tid / 16, ij = tid % 16, i = ij / 4, j = ij % 4;
        dists[bb][i][j] = (stage[bb][4 + i] + stage[bb][j]
                           - 2.0 * stage[bb][8 + i * 4 + j]) / (double)DLEN;
    }
    __syncthreads();

    if (tid < BATCH) {
        const int bb = tid;
        double best = 1e300;
        int bestp = 0;
        for (int p = 0; p < 24; ++p) {
            double c = 0.0;
#pragma unroll
            for (int i = 0; i < 4; ++i) c += dists[bb][i][PERMS[p][i]];
            if (c < best) { best = c; bestp = p; }   // strict < => first min (jnp.argmin)
        }
        mins[bb] = best;
#pragma unroll
        for (int i = 0; i < 4; ++i)
            out[1 + bb * 4 + i] = (float)PERMS[bestp][i];
    }
    __syncthreads();

    if (tid == 0) {
        double tot = 0.0;
        for (int bb = 0; bb < BATCH; ++bb) tot += mins[bb];
        out[0] = (float)tot;
    }
}

extern "C" void kernel_launch(void* const* d_in, const int* in_sizes, int n_in,
                              void* d_out, int out_size, void* d_ws, size_t ws_size,
                              hipStream_t stream) {
    const float* x = (const float*)d_in[0];
    const float* y = (const float*)d_in[1];
    float* out = (float*)d_out;
    float* ws  = (float*)d_ws;     // needs NVAL*NBLOCKS*4 = 12288 bytes

    pit_reduce<<<NBLOCKS, TPB, 0, stream>>>(x, y, ws);
    pit_finalize<<<1, 256, 0, stream>>>(ws, out);
}

// Round 13
// 28.703 us; speedup vs baseline: 2.4131x; 1.2491x over previous
//
#include <hip/hip_runtime.h>

// PIT loss: x,y [B=8, C=4, CH=2, T=262144] f32. D = CH*T = 524288.
// dists[b,i,j] = (sum(y[b,i]^2) + sum(x[b,j]^2) - 2*sum(x[b,j]*y[b,i])) / D
// total = sum_b min_p sum_i dists[b,i,perm[p][i]]; assignments[b] = argmin perm.
//
// R13 = R9 revert (best measured: 28.3 us). Stream-count curve measured:
// 4096 streams -> 29.3, 2048 -> 28.3 (this), 1024 -> 35.9 (clean, R12).
// nt loads (bypass L3 alloc, +10%), transposed ws, coalesced fp64 finalize.

#define BATCH   8
#define CDIM    4
#define DLEN    (2 * 262144)        // 524288 scalars per (b, c)
#define F4_PER_C (DLEN / 4)         // 131072 float4 per channel
#define BPB     32                  // blocks per batch
#define TPB     512
#define NVAL    24                  // 4 sx + 4 sy + 16 cross
#define NBLOCKS (BATCH * BPB)       // 256
#define NWAVES  (TPB / 64)          // 8

typedef float f4 __attribute__((ext_vector_type(4)));

// itertools.permutations(range(4)) lexicographic order
__device__ __constant__ int PERMS[24][4] = {
    {0,1,2,3},{0,1,3,2},{0,2,1,3},{0,2,3,1},{0,3,1,2},{0,3,2,1},
    {1,0,2,3},{1,0,3,2},{1,2,0,3},{1,2,3,0},{1,3,0,2},{1,3,2,0},
    {2,0,1,3},{2,0,3,1},{2,1,0,3},{2,1,3,0},{2,3,0,1},{2,3,1,0},
    {3,0,1,2},{3,0,2,1},{3,1,0,2},{3,1,2,0},{3,2,0,1},{3,2,1,0}
};

__global__ __launch_bounds__(TPB) void pit_reduce(const float* __restrict__ x,
                                                  const float* __restrict__ y,
                                                  float* __restrict__ ws) {
    const int b   = blockIdx.x / BPB;
    const int blk = blockIdx.x % BPB;
    const int tid = threadIdx.x;

    const int f4_per_block = F4_PER_C / BPB;     // 4096
    const int iters        = f4_per_block / TPB; // 8
    const int base_f4      = blk * f4_per_block;

    const f4* __restrict__ xb = (const f4*)(x + (size_t)b * CDIM * DLEN);
    const f4* __restrict__ yb = (const f4*)(y + (size_t)b * CDIM * DLEN);

    float sx[4] = {0.f, 0.f, 0.f, 0.f};
    float sy[4] = {0.f, 0.f, 0.f, 0.f};
    float cr[4][4] = {};

    for (int it = 0; it < iters; ++it) {
        const int p = base_f4 + it * TPB + tid;
        f4 xv[4], yv[4];
#pragma unroll
        for (int c = 0; c < 4; ++c)
            xv[c] = __builtin_nontemporal_load(&xb[(size_t)c * F4_PER_C + p]);
#pragma unroll
        for (int c = 0; c < 4; ++c)
            yv[c] = __builtin_nontemporal_load(&yb[(size_t)c * F4_PER_C + p]);
#pragma unroll
        for (int c = 0; c < 4; ++c) {
            sx[c] += xv[c].x * xv[c].x + xv[c].y * xv[c].y +
                     xv[c].z * xv[c].z + xv[c].w * xv[c].w;
            sy[c] += yv[c].x * yv[c].x + yv[c].y * yv[c].y +
                     yv[c].z * yv[c].z + yv[c].w * yv[c].w;
        }
#pragma unroll
        for (int i = 0; i < 4; ++i)
#pragma unroll
            for (int j = 0; j < 4; ++j)
                cr[i][j] += yv[i].x * xv[j].x + yv[i].y * xv[j].y +
                            yv[i].z * xv[j].z + yv[i].w * xv[j].w;
    }

    // pack 24 accumulators: [0..3]=sx, [4..7]=sy, [8..23]=cr[i][j]
    float v[NVAL];
#pragma unroll
    for (int c = 0; c < 4; ++c) { v[c] = sx[c]; v[4 + c] = sy[c]; }
#pragma unroll
    for (int i = 0; i < 4; ++i)
#pragma unroll
        for (int j = 0; j < 4; ++j) v[8 + i * 4 + j] = cr[i][j];

    // wave64 tree reduce (deterministic)
#pragma unroll
    for (int k = 0; k < NVAL; ++k) {
#pragma unroll
        for (int off = 32; off > 0; off >>= 1)
            v[k] += __shfl_down(v[k], off);
    }

    __shared__ float red[NWAVES][NVAL];
    const int wave = tid >> 6, lane = tid & 63;
    if (lane == 0) {
#pragma unroll
        for (int k = 0; k < NVAL; ++k) red[wave][k] = v[k];
    }
    __syncthreads();
    if (tid < NVAL) {
        float s = 0.f;
#pragma unroll
        for (int w = 0; w < NWAVES; ++w) s += red[w][tid];
        // transposed: ws[k][global_block] -> contiguous per-k rows of 256 floats
        ws[(size_t)tid * NBLOCKS + (b * BPB + blk)] = s;
    }
}

__global__ __launch_bounds__(256) void pit_finalize(const float* __restrict__ ws,
                                                    float* __restrict__ out) {
    __shared__ double stage[BATCH][NVAL];   // summed partials
    __shared__ double dists[BATCH][4][4];
    __shared__ double mins[BATCH];
    const int tid = threadIdx.x;

    // 192 active threads, (k major, b minor): the whole block reads the
    // 24 KiB ws span fully coalesced as float4.
    if (tid < BATCH * NVAL) {
        const int k = tid / BATCH, bb = tid % BATCH;
        const f4* p = (const f4*)(ws + (size_t)k * NBLOCKS + bb * BPB);
        double s0 = 0.0, s1 = 0.0, s2 = 0.0, s3 = 0.0;
#pragma unroll
        for (int q = 0; q < 8; q += 4) {         // 8 f4 = 32 partials
            f4 a = p[q + 0], c = p[q + 1], d = p[q + 2], e = p[q + 3];
            s0 += (double)a.x + (double)a.y + (double)a.z + (double)a.w;
            s1 += (double)c.x + (double)c.y + (double)c.z + (double)c.w;
            s2 += (double)d.x + (double)d.y + (double)d.z + (double)d.w;
            s3 += (double)e.x + (double)e.y + (double)e.z + (double)e.w;
        }
        stage[bb][k] = (s0 + s1) + (s2 + s3);
    }
    __syncthreads();

    if (tid < BATCH * 16) {                 // 128 threads
        const int bb = tid / 16, ij = tid % 16, i = ij / 4, j = ij % 4;
        dists[bb][i][j] = (stage[bb][4 + i] + stage[bb][j]
                           - 2.0 * stage[bb][8 + i * 4 + j]) / (double)DLEN;
    }
    __syncthreads();

    if (tid < BATCH) {
        const int bb = tid;
        double best = 1e300;
        int bestp = 0;
        for (int p = 0; p < 24; ++p) {
            double c = 0.0;
#pragma unroll
            for (int i = 0; i < 4; ++i) c += dists[bb][i][PERMS[p][i]];
            if (c < best) { best = c; bestp = p; }   // strict < => first min (jnp.argmin)
        }
        mins[bb] = best;
#pragma unroll
        for (int i = 0; i < 4; ++i)
            out[1 + bb * 4 + i] = (float)PERMS[bestp][i];
    }
    __syncthreads();

    if (tid == 0) {
        double tot = 0.0;
        for (int bb = 0; bb < BATCH; ++bb) tot += mins[bb];
        out[0] = (float)tot;
    }
}

extern "C" void kernel_launch(void* const* d_in, const int* in_sizes, int n_in,
                              void* d_out, int out_size, void* d_ws, size_t ws_size,
                              hipStream_t stream) {
    const float* x = (const float*)d_in[0];
    const float* y = (const float*)d_in[1];
    float* out = (float*)d_out;
    float* ws  = (float*)d_ws;     // needs NVAL*NBLOCKS*4 = 24576 bytes

    pit_reduce<<<NBLOCKS, TPB, 0, stream>>>(x, y, ws);
    pit_finalize<<<1, 256, 0, stream>>>(ws, out);
}